// Round 1
// baseline (14132.021 us; speedup 1.0000x reference)
//
#include <hip/hip_runtime.h>

#define B_    2
#define C_    64
#define D_    8
#define H_    56
#define W_    56
#define HW_   3136
#define DHW_  25088
#define G_    8
#define CPG_  8
#define K_    27
#define OFFC_ 648

// ---------------- offset conv: 3x3x3, C=64 -> OFFC=648, SAME, + bias ----------------
// grid (27, 56, 16): x = oc-tile(24), y = h, z = b*8+d.  block 256.
// LDS: input patch chunk (8 ic x 3 x 3 x 58) + weight chunk (24 oc x 8 ic x 27).
#define OCT 24
#define ICC 8
__global__ __launch_bounds__(256) void conv_off_kernel(
    const float* __restrict__ x, const float* __restrict__ wt,
    const float* __restrict__ bias, float* __restrict__ out)
{
    __shared__ float xs[ICC * 9 * 58];      // 16.7 KB
    __shared__ float ws[OCT * ICC * 27];    // 20.7 KB
    const int ot = blockIdx.x;
    const int h  = blockIdx.y;
    const int b  = blockIdx.z >> 3;
    const int d  = blockIdx.z & 7;
    const int t  = threadIdx.x;
    const int wl = t & 63;                  // w position (active if < 56)
    const int r  = t >> 6;                  // 0..3, wave-uniform
    const int wc = wl < 56 ? wl : 55;       // clamped for safe LDS reads

    float acc[6] = {0.f, 0.f, 0.f, 0.f, 0.f, 0.f};   // oc = ot*24 + r + 4*j

    for (int icc = 0; icc < C_; icc += ICC) {
        __syncthreads();
        // stage input patch: [ic][dd][hh][wi], wi in [0,58) = input w-1..56
        for (int i = t; i < ICC * 9 * 58; i += 256) {
            int ic  = i / 522;
            int rem = i - ic * 522;
            int dh  = rem / 58;
            int wi  = rem - dh * 58;
            int dd  = dh / 3, hh = dh - dd * 3;
            int ds  = d + dd - 1, hs = h + hh - 1, wsrc = wi - 1;
            float v = 0.f;
            if ((unsigned)ds < D_ && (unsigned)hs < H_ && (unsigned)wsrc < W_)
                v = x[((b * C_ + icc + ic) * D_ + ds) * HW_ + hs * W_ + wsrc];
            xs[i] = v;
        }
        // stage weight chunk: [ocl][ic][tap]
        for (int i = t; i < OCT * ICC * 27; i += 256) {
            int ocl = i / (ICC * 27);
            int rem = i - ocl * (ICC * 27);
            int ic  = rem / 27, tap = rem - ic * 27;
            ws[i] = wt[((ot * OCT + ocl) * C_ + icc + ic) * 27 + tap];
        }
        __syncthreads();

        for (int ic = 0; ic < ICC; ++ic) {
            #pragma unroll
            for (int tap = 0; tap < 27; ++tap) {
                int dd = tap / 9, hh = (tap / 3) % 3, ww = tap % 3;
                float xv = xs[(ic * 9 + dd * 3 + hh) * 58 + wc + ww];
                #pragma unroll
                for (int j = 0; j < 6; ++j)
                    acc[j] += xv * ws[((r + 4 * j) * ICC + ic) * 27 + tap];
            }
        }
    }
    if (wl < 56) {
        #pragma unroll
        for (int j = 0; j < 6; ++j) {
            int oc = ot * OCT + r + 4 * j;
            out[((b * OFFC_ + oc) * D_ + d) * HW_ + h * W_ + wl] = acc[j] + bias[oc];
        }
    }
}

// ---------------- deformable conv ----------------
// grid (14, 56, 16): x = w-tile(4), y = h, z = b*8+d.  block 256.
// stage 1: build col[4][1728] (trilinear gathers); stage 2: GEMV vs w_dc (chunked LDS).
#define WT 4
#define JC 108
__global__ __launch_bounds__(256) void deform_kernel(
    const float* __restrict__ x, const float* __restrict__ off,
    const float* __restrict__ wdc, float* __restrict__ out)
{
    __shared__ float col[WT][1728];         // 27.6 KB
    __shared__ float wsh[64][JC + 1];       // 27.9 KB (pad: stride 109, coprime w/ 32 banks)
    const int w0 = blockIdx.x * WT;
    const int h  = blockIdx.y;
    const int b  = blockIdx.z >> 3;
    const int d  = blockIdx.z & 7;
    const int t  = threadIdx.x;

    // ---- stage 1: gather ----
    for (int task = t; task < WT * 216; task += 256) {
        int w8 = task / 216;
        int gk = task - w8 * 216;
        int g  = gk / 27;
        int k  = gk - g * 27;
        int wpos = w0 + w8;
        int kd = k / 9 - 1, kh = (k / 3) % 3 - 1, kw = k - (k / 3) * 3 - 1;

        int obase = ((b * OFFC_ + (g * 27 + k) * 3) * D_ + d) * HW_ + h * W_ + wpos;
        float pd = off[obase]               + (float)(kd + d);
        float ph = off[obase + DHW_]        + (float)(kh + h);
        float pw = off[obase + 2 * DHW_]    + (float)(kw + wpos);

        float fd0 = floorf(pd), fh0 = floorf(ph), fw0 = floorf(pw);
        float fd = pd - fd0, fh = ph - fh0, fw = pw - fw0;
        int d0 = (int)fd0, h0 = (int)fh0, w0i = (int)fw0;

        int   offs[8];
        float wts[8];
        #pragma unroll
        for (int tp = 0; tp < 8; ++tp) {
            int dd = tp >> 2, hh = (tp >> 1) & 1, ww2 = tp & 1;
            int di = d0 + dd, hi = h0 + hh, wi = w0i + ww2;
            float wgt = (dd ? fd : 1.f - fd) * (hh ? fh : 1.f - fh) * (ww2 ? fw : 1.f - fw);
            bool valid = ((unsigned)di < D_) && ((unsigned)hi < H_) && ((unsigned)wi < W_);
            offs[tp] = valid ? di * HW_ + hi * W_ + wi : 0;
            wts[tp]  = valid ? wgt : 0.f;
        }

        const float* xb = x + (b * C_ + g * CPG_) * DHW_;
        int cbase = g * 216 + k;            // (g*8+c)*27 + k, c added as c*27
        for (int c = 0; c < CPG_; ++c) {
            float v = 0.f;
            #pragma unroll
            for (int tp = 0; tp < 8; ++tp)
                v += xb[c * DHW_ + offs[tp]] * wts[tp];
            col[w8][cbase + c * 27] = v;
        }
    }
    __syncthreads();

    // ---- stage 2: out[o] = sum_j col[w][j] * wdc[o][j] ----
    const int o  = t & 63;                  // lane -> output channel
    const int wq = t >> 6;                  // wave -> w within tile
    float acc = 0.f;
    for (int jc = 0; jc < 1728; jc += JC) {
        if (jc) __syncthreads();
        for (int i = t; i < 64 * JC; i += 256) {
            int oo = i / JC, jj = i - oo * JC;
            wsh[oo][jj] = wdc[oo * 1728 + jc + jj];
        }
        __syncthreads();
        #pragma unroll 4
        for (int jj = 0; jj < JC; ++jj)
            acc += col[wq][jc + jj] * wsh[o][jj];
    }
    out[(b * C_ + o) * DHW_ + d * HW_ + h * W_ + w0 + wq] = acc;
}

// ---------------- batchnorm stats: one block per channel ----------------
__global__ __launch_bounds__(256) void bn_stats_kernel(
    const float* __restrict__ hbuf, float* __restrict__ stats)
{
    const int c = blockIdx.x;
    const int t = threadIdx.x;
    float s = 0.f, s2 = 0.f;
    for (int b = 0; b < B_; ++b) {
        const float* p = hbuf + (b * C_ + c) * DHW_;
        for (int i = t; i < DHW_; i += 256) {
            float v = p[i];
            s += v; s2 += v * v;
        }
    }
    #pragma unroll
    for (int o = 32; o > 0; o >>= 1) {
        s  += __shfl_down(s, o);
        s2 += __shfl_down(s2, o);
    }
    __shared__ float rs[4], rq[4];
    if ((t & 63) == 0) { rs[t >> 6] = s; rq[t >> 6] = s2; }
    __syncthreads();
    if (t == 0) {
        float ts = rs[0] + rs[1] + rs[2] + rs[3];
        float tq = rq[0] + rq[1] + rq[2] + rq[3];
        float inv = 1.f / (float)(B_ * DHW_);
        float m   = ts * inv;
        float var = tq * inv - m * m;
        stats[c]      = m;
        stats[C_ + c] = rsqrtf(fmaxf(var, 0.f) + 1e-5f);
    }
}

// ---------------- bn + relu (in place) ----------------
__global__ __launch_bounds__(256) void bn_relu_kernel(
    float* __restrict__ hbuf, const float* __restrict__ stats,
    const float* __restrict__ gamma, const float* __restrict__ beta)
{
    const int n = B_ * C_ * DHW_;
    for (int i = blockIdx.x * 256 + threadIdx.x; i < n; i += gridDim.x * 256) {
        int c = (i / DHW_) & (C_ - 1);
        float v = (hbuf[i] - stats[c]) * stats[C_ + c] * gamma[c] + beta[c];
        hbuf[i] = v > 0.f ? v : 0.f;
    }
}

// ---------------- bn + residual add + relu (in place on d_out) ----------------
__global__ __launch_bounds__(256) void bn_add_relu_kernel(
    float* __restrict__ hbuf, const float* __restrict__ xres,
    const float* __restrict__ stats,
    const float* __restrict__ gamma, const float* __restrict__ beta)
{
    const int n = B_ * C_ * DHW_;
    for (int i = blockIdx.x * 256 + threadIdx.x; i < n; i += gridDim.x * 256) {
        int c = (i / DHW_) & (C_ - 1);
        float v = (hbuf[i] - stats[c]) * stats[C_ + c] * gamma[c] + beta[c] + xres[i];
        hbuf[i] = v > 0.f ? v : 0.f;
    }
}

extern "C" void kernel_launch(void* const* d_in, const int* in_sizes, int n_in,
                              void* d_out, int out_size, void* d_ws, size_t ws_size,
                              hipStream_t stream)
{
    const float* x      = (const float*)d_in[0];
    const float* w_off1 = (const float*)d_in[1];
    const float* b_off1 = (const float*)d_in[2];
    const float* w_dc1  = (const float*)d_in[3];
    const float* gamma1 = (const float*)d_in[4];
    const float* beta1  = (const float*)d_in[5];
    const float* w_off2 = (const float*)d_in[6];
    const float* b_off2 = (const float*)d_in[7];
    const float* w_dc2  = (const float*)d_in[8];
    const float* gamma2 = (const float*)d_in[9];
    const float* beta2  = (const float*)d_in[10];
    float* out = (float*)d_out;

    float* off   = (float*)d_ws;                        // 32,514,048 f32 (130 MB)
    float* h1    = off + (size_t)B_ * OFFC_ * DHW_;     //  3,211,264 f32 (12.85 MB)
    float* stats = h1 + (size_t)B_ * C_ * DHW_;         //  128 f32

    dim3 cgrid(OFFC_ / OCT, H_, B_ * D_);
    dim3 dgrid(W_ / WT, H_, B_ * D_);
    const int egrid = 1024;

    conv_off_kernel  <<<cgrid, 256, 0, stream>>>(x, w_off1, b_off1, off);
    deform_kernel    <<<dgrid, 256, 0, stream>>>(x, off, w_dc1, h1);
    bn_stats_kernel  <<<C_,    256, 0, stream>>>(h1, stats);
    bn_relu_kernel   <<<egrid, 256, 0, stream>>>(h1, stats, gamma1, beta1);
    conv_off_kernel  <<<cgrid, 256, 0, stream>>>(h1, w_off2, b_off2, off);
    deform_kernel    <<<dgrid, 256, 0, stream>>>(h1, off, w_dc2, out);
    bn_stats_kernel  <<<C_,    256, 0, stream>>>(out, stats);
    bn_add_relu_kernel<<<egrid,256, 0, stream>>>(out, x, stats, gamma2, beta2);
}

// Round 2
// 7660.853 us; speedup vs baseline: 1.8447x; 1.8447x over previous
//
#include <hip/hip_runtime.h>

#define B_    2
#define C_    64
#define D_    8
#define H_    56
#define W_    56
#define HW_   3136
#define DHW_  25088
#define G_    8
#define CPG_  8
#define K_    27
#define OFFC_ 648

typedef __attribute__((ext_vector_type(8))) short  bf16x8;
typedef __attribute__((ext_vector_type(4))) float  f32x4;
typedef __attribute__((ext_vector_type(8))) unsigned short ushort8;

__device__ __forceinline__ unsigned short f2bf(float f) {
    unsigned u = __float_as_uint(f);
    u = (u + 0x7FFFu + ((u >> 16) & 1u)) >> 16;
    return (unsigned short)u;
}

// ---------------- weight transpose: w[oc][ic][tap] f32 -> wT[oc][icc*216 + tap*8 + icl] bf16 ----
__global__ __launch_bounds__(256) void wt_transpose_kernel(
    const float* __restrict__ wt, unsigned short* __restrict__ wT)
{
    int i = blockIdx.x * 256 + threadIdx.x;           // over 648*1728
    if (i >= OFFC_ * 1728) return;
    int oc = i / 1728, k = i - oc * 1728;
    int icc = k / 216, r = k - icc * 216;
    int tap = r >> 3, icl = r & 7;
    wT[i] = f2bf(wt[(size_t)oc * 1728 + (icc * 8 + icl) * 27 + tap]);
}

// ---------------- offset conv as implicit GEMM (bf16 MFMA) ----------------
// grid (11, 49, 16): x = oc-tile(64), y = pos-tile(64 within HW), z = b*8+d. block 256 (4 waves 2x2).
#define CROW 512   // bytes per LDS row (224 bf16 padded to 256)

__device__ __forceinline__ int swz(int row, int kByte) {
    return row * CROW + (kByte ^ ((row & 7) << 4));
}

__global__ __launch_bounds__(256) void conv_off_mfma_kernel(
    const float* __restrict__ x, const unsigned short* __restrict__ wT,
    const float* __restrict__ bias, float* __restrict__ out)
{
    __shared__ __align__(16) char colb[64 * CROW];     // 32 KB  im2col tile
    __shared__ __align__(16) char wb[64 * CROW];       // 32 KB  weight tile
    __shared__ __align__(16) unsigned short xr[12 * 64 * 8]; // 12 KB raw patch, ic innermost

    const int oc0  = blockIdx.x * 64;
    const int pos0 = blockIdx.y * 64;
    const int b    = blockIdx.z >> 3;
    const int d    = blockIdx.z & 7;
    const int h0   = pos0 / 56;
    const int t    = threadIdx.x;
    const int lane = t & 63;
    const int wv   = t >> 6;
    const int wrow = wv >> 1;   // oc half
    const int wcol = wv & 1;    // pos half

    f32x4 acc[2][2];
    #pragma unroll
    for (int i = 0; i < 2; ++i)
        #pragma unroll
        for (int j = 0; j < 2; ++j)
            acc[i][j] = (f32x4){0.f, 0.f, 0.f, 0.f};

    for (int icc = 0; icc < 8; ++icc) {
        __syncthreads();
        // --- stage raw patch: xr[dd(3)][hl(4)][w(64)][ic(8)] bf16, coalesced global reads ---
        for (int i = t; i < 768; i += 256) {
            int w  = i & 63, dh = i >> 6;
            int dd = dh >> 2, hl = dh & 3;
            int ds = d + dd - 1, hs = h0 - 1 + hl, ws = w - 1;
            bool ok = (unsigned)ds < 8u && (unsigned)hs < 56u && (unsigned)ws < 56u;
            int dsC = ok ? ds : 0, hsC = ok ? hs : 0, wsC = ok ? ws : 0;
            const float* xp = x + (((size_t)b * 64 + icc * 8) * 8 + dsC) * HW_ + hsC * 56 + wsC;
            ushort8 v;
            #pragma unroll
            for (int ic = 0; ic < 8; ++ic)
                v[ic] = ok ? f2bf(xp[ic * DHW_]) : (unsigned short)0;
            *(ushort8*)&xr[i * 8] = v;
        }
        // --- stage weights: wb[oc][k] with k = tap*8+icl (pad k>=216 with 0), u32 pairs ---
        for (int i = t; i < 7168; i += 256) {
            int oc = i / 112, k2 = i - oc * 112, k = k2 * 2;
            int ocg = oc0 + oc;
            unsigned vv = 0;
            if (ocg < OFFC_ && k < 216)
                vv = *(const unsigned*)(wT + (size_t)ocg * 1728 + icc * 216 + k);
            *(unsigned*)(wb + swz(oc, k2 * 4)) = vv;
        }
        __syncthreads();
        // --- im2col build: col[pos][tap*8+icl] from xr, one b128 read + write per (pos,tap) ---
        for (int i = t; i < 1792; i += 256) {
            int pl = i & 63, tap = i >> 6;          // tap 0..27 (27 = zero pad)
            ushort8 v = {0, 0, 0, 0, 0, 0, 0, 0};
            if (tap < 27) {
                int p = pos0 + pl, hp = p / 56, wp = p - hp * 56;
                int dd = tap / 9, hh = (tap / 3) % 3, ww = tap - (tap / 3) * 3;
                int hl = hp - h0 + hh, wi = wp + ww;
                v = *(const ushort8*)&xr[((dd * 4 + hl) * 64 + wi) * 8];
            }
            *(ushort8*)(colb + swz(pl, tap * 16)) = v;
        }
        __syncthreads();
        // --- MFMA: 7 K-steps of 32 ---
        #pragma unroll
        for (int kk = 0; kk < 7; ++kk) {
            int kb = kk * 64 + (lane >> 4) * 16;
            bf16x8 a0 = *(const bf16x8*)(wb   + swz(wrow * 32 +      (lane & 15), kb));
            bf16x8 a1 = *(const bf16x8*)(wb   + swz(wrow * 32 + 16 + (lane & 15), kb));
            bf16x8 b0 = *(const bf16x8*)(colb + swz(wcol * 32 +      (lane & 15), kb));
            bf16x8 b1 = *(const bf16x8*)(colb + swz(wcol * 32 + 16 + (lane & 15), kb));
            acc[0][0] = __builtin_amdgcn_mfma_f32_16x16x32_bf16(a0, b0, acc[0][0], 0, 0, 0);
            acc[0][1] = __builtin_amdgcn_mfma_f32_16x16x32_bf16(a0, b1, acc[0][1], 0, 0, 0);
            acc[1][0] = __builtin_amdgcn_mfma_f32_16x16x32_bf16(a1, b0, acc[1][0], 0, 0, 0);
            acc[1][1] = __builtin_amdgcn_mfma_f32_16x16x32_bf16(a1, b1, acc[1][1], 0, 0, 0);
        }
    }

    // --- store: D row=(lane>>4)*4+r (oc), col=lane&15 (pos) ---
    #pragma unroll
    for (int oa = 0; oa < 2; ++oa)
        #pragma unroll
        for (int pb = 0; pb < 2; ++pb)
            #pragma unroll
            for (int r = 0; r < 4; ++r) {
                int ocg = oc0 + wrow * 32 + oa * 16 + (lane >> 4) * 4 + r;
                if (ocg < OFFC_) {
                    int p = pos0 + wcol * 32 + pb * 16 + (lane & 15);
                    out[(((size_t)b * OFFC_ + ocg) * 8 + d) * HW_ + p] = acc[oa][pb][r] + bias[ocg];
                }
            }
}

// ---------------- deformable conv (unchanged from round 1) ----------------
#define WT 4
#define JC 108
__global__ __launch_bounds__(256) void deform_kernel(
    const float* __restrict__ x, const float* __restrict__ off,
    const float* __restrict__ wdc, float* __restrict__ out)
{
    __shared__ float col[WT][1728];
    __shared__ float wsh[64][JC + 1];
    const int w0 = blockIdx.x * WT;
    const int h  = blockIdx.y;
    const int b  = blockIdx.z >> 3;
    const int d  = blockIdx.z & 7;
    const int t  = threadIdx.x;

    for (int task = t; task < WT * 216; task += 256) {
        int w8 = task / 216;
        int gk = task - w8 * 216;
        int g  = gk / 27;
        int k  = gk - g * 27;
        int wpos = w0 + w8;
        int kd = k / 9 - 1, kh = (k / 3) % 3 - 1, kw = k - (k / 3) * 3 - 1;

        int obase = ((b * OFFC_ + (g * 27 + k) * 3) * D_ + d) * HW_ + h * W_ + wpos;
        float pd = off[obase]            + (float)(kd + d);
        float ph = off[obase + DHW_]     + (float)(kh + h);
        float pw = off[obase + 2 * DHW_] + (float)(kw + wpos);

        float fd0 = floorf(pd), fh0 = floorf(ph), fw0 = floorf(pw);
        float fd = pd - fd0, fh = ph - fh0, fw = pw - fw0;
        int d0 = (int)fd0, h0 = (int)fh0, w0i = (int)fw0;

        int   offs[8];
        float wts[8];
        #pragma unroll
        for (int tp = 0; tp < 8; ++tp) {
            int dd = tp >> 2, hh = (tp >> 1) & 1, ww2 = tp & 1;
            int di = d0 + dd, hi = h0 + hh, wi = w0i + ww2;
            float wgt = (dd ? fd : 1.f - fd) * (hh ? fh : 1.f - fh) * (ww2 ? fw : 1.f - fw);
            bool valid = ((unsigned)di < D_) && ((unsigned)hi < H_) && ((unsigned)wi < W_);
            offs[tp] = valid ? di * HW_ + hi * W_ + wi : 0;
            wts[tp]  = valid ? wgt : 0.f;
        }

        const float* xb = x + (b * C_ + g * CPG_) * DHW_;
        int cbase = g * 216 + k;
        for (int c = 0; c < CPG_; ++c) {
            float v = 0.f;
            #pragma unroll
            for (int tp = 0; tp < 8; ++tp)
                v += xb[c * DHW_ + offs[tp]] * wts[tp];
            col[w8][cbase + c * 27] = v;
        }
    }
    __syncthreads();

    const int o  = t & 63;
    const int wq = t >> 6;
    float acc = 0.f;
    for (int jc = 0; jc < 1728; jc += JC) {
        if (jc) __syncthreads();
        for (int i = t; i < 64 * JC; i += 256) {
            int oo = i / JC, jj = i - oo * JC;
            wsh[oo][jj] = wdc[oo * 1728 + jc + jj];
        }
        __syncthreads();
        #pragma unroll 4
        for (int jj = 0; jj < JC; ++jj)
            acc += col[wq][jc + jj] * wsh[o][jj];
    }
    out[(b * C_ + o) * DHW_ + d * HW_ + h * W_ + w0 + wq] = acc;
}

// ---------------- batchnorm stats ----------------
__global__ __launch_bounds__(256) void bn_stats_kernel(
    const float* __restrict__ hbuf, float* __restrict__ stats)
{
    const int c = blockIdx.x;
    const int t = threadIdx.x;
    float s = 0.f, s2 = 0.f;
    for (int b = 0; b < B_; ++b) {
        const float* p = hbuf + (b * C_ + c) * DHW_;
        for (int i = t; i < DHW_; i += 256) {
            float v = p[i];
            s += v; s2 += v * v;
        }
    }
    #pragma unroll
    for (int o = 32; o > 0; o >>= 1) {
        s  += __shfl_down(s, o);
        s2 += __shfl_down(s2, o);
    }
    __shared__ float rs[4], rq[4];
    if ((t & 63) == 0) { rs[t >> 6] = s; rq[t >> 6] = s2; }
    __syncthreads();
    if (t == 0) {
        float ts = rs[0] + rs[1] + rs[2] + rs[3];
        float tq = rq[0] + rq[1] + rq[2] + rq[3];
        float inv = 1.f / (float)(B_ * DHW_);
        float m   = ts * inv;
        float var = tq * inv - m * m;
        stats[c]      = m;
        stats[C_ + c] = rsqrtf(fmaxf(var, 0.f) + 1e-5f);
    }
}

__global__ __launch_bounds__(256) void bn_relu_kernel(
    float* __restrict__ hbuf, const float* __restrict__ stats,
    const float* __restrict__ gamma, const float* __restrict__ beta)
{
    const int n = B_ * C_ * DHW_;
    for (int i = blockIdx.x * 256 + threadIdx.x; i < n; i += gridDim.x * 256) {
        int c = (i / DHW_) & (C_ - 1);
        float v = (hbuf[i] - stats[c]) * stats[C_ + c] * gamma[c] + beta[c];
        hbuf[i] = v > 0.f ? v : 0.f;
    }
}

__global__ __launch_bounds__(256) void bn_add_relu_kernel(
    float* __restrict__ hbuf, const float* __restrict__ xres,
    const float* __restrict__ stats,
    const float* __restrict__ gamma, const float* __restrict__ beta)
{
    const int n = B_ * C_ * DHW_;
    for (int i = blockIdx.x * 256 + threadIdx.x; i < n; i += gridDim.x * 256) {
        int c = (i / DHW_) & (C_ - 1);
        float v = (hbuf[i] - stats[c]) * stats[C_ + c] * gamma[c] + beta[c] + xres[i];
        hbuf[i] = v > 0.f ? v : 0.f;
    }
}

extern "C" void kernel_launch(void* const* d_in, const int* in_sizes, int n_in,
                              void* d_out, int out_size, void* d_ws, size_t ws_size,
                              hipStream_t stream)
{
    const float* x      = (const float*)d_in[0];
    const float* w_off1 = (const float*)d_in[1];
    const float* b_off1 = (const float*)d_in[2];
    const float* w_dc1  = (const float*)d_in[3];
    const float* gamma1 = (const float*)d_in[4];
    const float* beta1  = (const float*)d_in[5];
    const float* w_off2 = (const float*)d_in[6];
    const float* b_off2 = (const float*)d_in[7];
    const float* w_dc2  = (const float*)d_in[8];
    const float* gamma2 = (const float*)d_in[9];
    const float* beta2  = (const float*)d_in[10];
    float* out = (float*)d_out;

    float* off   = (float*)d_ws;                        // 32,514,048 f32 (130 MB)
    float* h1    = off + (size_t)B_ * OFFC_ * DHW_;     //  3,211,264 f32
    float* stats = h1 + (size_t)B_ * C_ * DHW_;         //  128 f32

    // weight-transpose scratch lives in d_out (dead until deform2 overwrites it)
    unsigned short* wTs = (unsigned short*)d_out;       // 648*1728 ushort = 2.24 MB << 12.8 MB

    dim3 cgrid(11, 49, B_ * D_);
    dim3 dgrid(W_ / WT, H_, B_ * D_);
    const int egrid = 1024;
    const int tgrid = (OFFC_ * 1728 + 255) / 256;

    wt_transpose_kernel<<<tgrid, 256, 0, stream>>>(w_off1, wTs);
    conv_off_mfma_kernel<<<cgrid, 256, 0, stream>>>(x, wTs, b_off1, off);
    deform_kernel      <<<dgrid, 256, 0, stream>>>(x, off, w_dc1, h1);
    bn_stats_kernel    <<<C_,    256, 0, stream>>>(h1, stats);
    bn_relu_kernel     <<<egrid, 256, 0, stream>>>(h1, stats, gamma1, beta1);

    wt_transpose_kernel<<<tgrid, 256, 0, stream>>>(w_off2, wTs);
    conv_off_mfma_kernel<<<cgrid, 256, 0, stream>>>(h1, wTs, b_off2, off);
    deform_kernel      <<<dgrid, 256, 0, stream>>>(h1, off, w_dc2, out);
    bn_stats_kernel    <<<C_,    256, 0, stream>>>(out, stats);
    bn_add_relu_kernel <<<egrid, 256, 0, stream>>>(out, x, stats, gamma2, beta2);
}

// Round 3
// 2663.631 us; speedup vs baseline: 5.3055x; 2.8761x over previous
//
#include <hip/hip_runtime.h>

#define B_    2
#define C_    64
#define D_    8
#define H_    56
#define W_    56
#define HW_   3136
#define DHW_  25088
#define G_    8
#define K_    27
#define OFFC_ 648

typedef __attribute__((ext_vector_type(8))) short  bf16x8;
typedef __attribute__((ext_vector_type(4))) float  f32x4;
typedef __attribute__((ext_vector_type(8))) unsigned short ushort8;

__device__ __forceinline__ unsigned short f2bf(float f) {
    unsigned u = __float_as_uint(f);
    u = (u + 0x7FFFu + ((u >> 16) & 1u)) >> 16;
    return (unsigned short)u;
}
__device__ __forceinline__ float bf2f(unsigned short u) {
    return __uint_as_float(((unsigned)u) << 16);
}

// ---- pack x: f32 [b][c][d][h][w] -> bf16 [b][g][d][h][w][c8] ----
__global__ __launch_bounds__(256) void pack_kernel(
    const float* __restrict__ x, unsigned short* __restrict__ xp)
{
    int i = blockIdx.x * 256 + threadIdx.x;          // over B*G*DHW
    if (i >= B_ * G_ * DHW_) return;
    int b = i / (G_ * DHW_);
    int rem = i - b * G_ * DHW_;
    int g = rem / DHW_, dhw = rem - g * DHW_;
    const float* src = x + (size_t)(b * C_ + g * 8) * DHW_ + dhw;
    ushort8 v;
    #pragma unroll
    for (int c = 0; c < 8; ++c) v[c] = f2bf(src[c * DHW_]);
    *(ushort8*)(xp + (size_t)i * 8) = v;
}

// ---- weight transpose: w[oc][ic][27] f32 -> wT[oc][g*216 + tap*8 + c] bf16 ----
__global__ __launch_bounds__(256) void wt_transpose_kernel(
    const float* __restrict__ wt, unsigned short* __restrict__ wT, int total)
{
    int i = blockIdx.x * 256 + threadIdx.x;
    if (i >= total) return;
    int oc = i / 1728, k = i - oc * 1728;
    int icc = k / 216, r = k - icc * 216;
    int tap = r >> 3, icl = r & 7;
    wT[i] = f2bf(wt[(size_t)oc * 1728 + (icc * 8 + icl) * 27 + tap]);
}

#define CROW 512
__device__ __forceinline__ int swz(int row, int kByte) {
    return row * CROW + (kByte ^ ((row & 7) << 4));
}

// ---- offset conv implicit GEMM: xp packed bf16 in, off bf16 out ----
__global__ __launch_bounds__(256) void conv_off_mfma_kernel(
    const unsigned short* __restrict__ xp, const unsigned short* __restrict__ wT,
    const float* __restrict__ bias, unsigned short* __restrict__ out)
{
    __shared__ __align__(16) char colb[64 * CROW];            // 32 KB
    __shared__ __align__(16) char wb[64 * CROW];              // 32 KB
    __shared__ __align__(16) unsigned short xr[12 * 64 * 8];  // 12 KB

    const int oc0  = blockIdx.x * 64;
    const int pos0 = blockIdx.y * 64;
    const int b    = blockIdx.z >> 3;
    const int d    = blockIdx.z & 7;
    const int h0   = pos0 / 56;
    const int t    = threadIdx.x;
    const int lane = t & 63;
    const int wv   = t >> 6;
    const int wrow = wv >> 1, wcol = wv & 1;

    f32x4 acc[2][2];
    #pragma unroll
    for (int i = 0; i < 2; ++i)
        #pragma unroll
        for (int j = 0; j < 2; ++j) acc[i][j] = (f32x4){0.f, 0.f, 0.f, 0.f};

    for (int g = 0; g < 8; ++g) {
        __syncthreads();
        // raw patch: xr[dd3][hl4][w64][c8], one 16B load each
        for (int i = t; i < 768; i += 256) {
            int w = i & 63, dh = i >> 6;
            int dd = dh >> 2, hl = dh & 3;
            int ds = d + dd - 1, hs = h0 - 1 + hl, wsrc = w - 1;
            ushort8 v = {0, 0, 0, 0, 0, 0, 0, 0};
            if ((unsigned)ds < 8u && (unsigned)hs < 56u && (unsigned)wsrc < 56u)
                v = *(const ushort8*)(xp + ((size_t)((b * 8 + g) * 8 + ds) * HW_ + hs * 56 + wsrc) * 8);
            *(ushort8*)&xr[i * 8] = v;
        }
        // weights
        for (int i = t; i < 7168; i += 256) {
            int oc = i / 112, k2 = i - oc * 112, k = k2 * 2;
            int ocg = oc0 + oc;
            unsigned vv = 0;
            if (ocg < OFFC_ && k < 216)
                vv = *(const unsigned*)(wT + (size_t)ocg * 1728 + g * 216 + k);
            *(unsigned*)(wb + swz(oc, k2 * 4)) = vv;
        }
        __syncthreads();
        // im2col: b128 read + b128 write
        for (int i = t; i < 1792; i += 256) {
            int pl = i & 63, tap = i >> 6;
            ushort8 v = {0, 0, 0, 0, 0, 0, 0, 0};
            if (tap < 27) {
                int p = pos0 + pl, hp = p / 56, wp = p - hp * 56;
                int dd = tap / 9, hh = (tap / 3) % 3, ww = tap - (tap / 3) * 3;
                int hl = hp - h0 + hh, wi = wp + ww;
                v = *(const ushort8*)&xr[((dd * 4 + hl) * 64 + wi) * 8];
            }
            *(ushort8*)(colb + swz(pl, tap * 16)) = v;
        }
        __syncthreads();
        #pragma unroll
        for (int kk = 0; kk < 7; ++kk) {
            int kb = kk * 64 + (lane >> 4) * 16;
            bf16x8 a0 = *(const bf16x8*)(wb   + swz(wrow * 32 +      (lane & 15), kb));
            bf16x8 a1 = *(const bf16x8*)(wb   + swz(wrow * 32 + 16 + (lane & 15), kb));
            bf16x8 b0 = *(const bf16x8*)(colb + swz(wcol * 32 +      (lane & 15), kb));
            bf16x8 b1 = *(const bf16x8*)(colb + swz(wcol * 32 + 16 + (lane & 15), kb));
            acc[0][0] = __builtin_amdgcn_mfma_f32_16x16x32_bf16(a0, b0, acc[0][0], 0, 0, 0);
            acc[0][1] = __builtin_amdgcn_mfma_f32_16x16x32_bf16(a0, b1, acc[0][1], 0, 0, 0);
            acc[1][0] = __builtin_amdgcn_mfma_f32_16x16x32_bf16(a1, b0, acc[1][0], 0, 0, 0);
            acc[1][1] = __builtin_amdgcn_mfma_f32_16x16x32_bf16(a1, b1, acc[1][1], 0, 0, 0);
        }
    }

    #pragma unroll
    for (int oa = 0; oa < 2; ++oa)
        #pragma unroll
        for (int pb = 0; pb < 2; ++pb)
            #pragma unroll
            for (int r = 0; r < 4; ++r) {
                int ocg = oc0 + wrow * 32 + oa * 16 + (lane >> 4) * 4 + r;
                if (ocg < OFFC_) {
                    int p = pos0 + wcol * 32 + pb * 16 + (lane & 15);
                    out[((size_t)(b * OFFC_ + ocg) * 8 + d) * HW_ + p] = f2bf(acc[oa][pb][r] + bias[ocg]);
                }
            }
}

// ---- deformable conv implicit GEMM ----
// grid (49, 16): x = pos tile, y = b*8+d. block 256, 4 waves 2x2 over 64oc x 64pos.
__global__ __launch_bounds__(256) void deform_mfma_kernel(
    const unsigned short* __restrict__ xp, const unsigned short* __restrict__ off,
    const unsigned short* __restrict__ wT, float* __restrict__ out)
{
    __shared__ __align__(16) char colb[64 * CROW];   // 32 KB
    __shared__ __align__(16) char wb[64 * CROW];     // 32 KB

    const int pos0 = blockIdx.x * 64;
    const int b    = blockIdx.y >> 3;
    const int d    = blockIdx.y & 7;
    const int t    = threadIdx.x;
    const int lane = t & 63, wv = t >> 6;
    const int wrow = wv >> 1, wcol = wv & 1;

    f32x4 acc[2][2];
    #pragma unroll
    for (int i = 0; i < 2; ++i)
        #pragma unroll
        for (int j = 0; j < 2; ++j) acc[i][j] = (f32x4){0.f, 0.f, 0.f, 0.f};

    for (int g = 0; g < 8; ++g) {
        __syncthreads();
        // weights for this group
        for (int i = t; i < 7168; i += 256) {
            int oc = i / 112, k2 = i - oc * 112, k = k2 * 2;
            unsigned vv = (k < 216) ? *(const unsigned*)(wT + (size_t)oc * 1728 + g * 216 + k) : 0u;
            *(unsigned*)(wb + swz(oc, k2 * 4)) = vv;
        }
        // gather: 27 taps x 64 pos, consecutive threads = consecutive pos (coalesced off reads)
        for (int i = t; i < 1728; i += 256) {
            int pos = i & 63, kk = i >> 6;
            int p = pos0 + pos;
            int hq = p / 56, wq = p - hq * 56;
            int kd = kk / 9 - 1, kh = (kk / 3) % 3 - 1, kw = kk - (kk / 3) * 3 - 1;
            size_t ob = ((size_t)(b * OFFC_ + (g * 27 + kk) * 3) * 8 + d) * HW_ + p;
            float pd = bf2f(off[ob])            + (float)(kd + d);
            float ph = bf2f(off[ob + DHW_])     + (float)(kh + hq);
            float pw = bf2f(off[ob + 2 * DHW_]) + (float)(kw + wq);
            float fd0 = floorf(pd), fh0 = floorf(ph), fw0 = floorf(pw);
            float fd = pd - fd0, fh = ph - fh0, fw = pw - fw0;
            int d0 = (int)fd0, h0i = (int)fh0, w0i = (int)fw0;
            const unsigned short* xb = xp + (size_t)(b * 8 + g) * 8 * HW_ * 8;
            float a[8] = {0.f, 0.f, 0.f, 0.f, 0.f, 0.f, 0.f, 0.f};
            #pragma unroll
            for (int tp = 0; tp < 8; ++tp) {
                int dd = tp >> 2, hh = (tp >> 1) & 1, ww = tp & 1;
                int di = d0 + dd, hi = h0i + hh, wi = w0i + ww;
                float wgt = (dd ? fd : 1.f - fd) * (hh ? fh : 1.f - fh) * (ww ? fw : 1.f - fw);
                bool valid = ((unsigned)di < 8u) && ((unsigned)hi < 56u) && ((unsigned)wi < 56u);
                wgt = valid ? wgt : 0.f;
                int dc = valid ? di : 0, hc = valid ? hi : 0, wc = valid ? wi : 0;
                ushort8 v = *(const ushort8*)(xb + ((size_t)dc * HW_ + hc * 56 + wc) * 8);
                #pragma unroll
                for (int c = 0; c < 8; ++c) a[c] += bf2f(v[c]) * wgt;
            }
            ushort8 o8;
            #pragma unroll
            for (int c = 0; c < 8; ++c) o8[c] = f2bf(a[c]);
            *(ushort8*)(colb + swz(pos, kk * 16)) = o8;
        }
        // zero-pad k = 216..223
        if (t < 64) {
            ushort8 z = {0, 0, 0, 0, 0, 0, 0, 0};
            *(ushort8*)(colb + swz(t, 432)) = z;
        }
        __syncthreads();
        #pragma unroll
        for (int kk = 0; kk < 7; ++kk) {
            int kb = kk * 64 + (lane >> 4) * 16;
            bf16x8 a0 = *(const bf16x8*)(wb   + swz(wrow * 32 +      (lane & 15), kb));
            bf16x8 a1 = *(const bf16x8*)(wb   + swz(wrow * 32 + 16 + (lane & 15), kb));
            bf16x8 b0 = *(const bf16x8*)(colb + swz(wcol * 32 +      (lane & 15), kb));
            bf16x8 b1 = *(const bf16x8*)(colb + swz(wcol * 32 + 16 + (lane & 15), kb));
            acc[0][0] = __builtin_amdgcn_mfma_f32_16x16x32_bf16(a0, b0, acc[0][0], 0, 0, 0);
            acc[0][1] = __builtin_amdgcn_mfma_f32_16x16x32_bf16(a0, b1, acc[0][1], 0, 0, 0);
            acc[1][0] = __builtin_amdgcn_mfma_f32_16x16x32_bf16(a1, b0, acc[1][0], 0, 0, 0);
            acc[1][1] = __builtin_amdgcn_mfma_f32_16x16x32_bf16(a1, b1, acc[1][1], 0, 0, 0);
        }
    }

    #pragma unroll
    for (int oa = 0; oa < 2; ++oa)
        #pragma unroll
        for (int pb = 0; pb < 2; ++pb)
            #pragma unroll
            for (int r = 0; r < 4; ++r) {
                int oc = wrow * 32 + oa * 16 + (lane >> 4) * 4 + r;
                int p  = pos0 + wcol * 32 + pb * 16 + (lane & 15);
                out[((size_t)(b * C_ + oc) * 8 + d) * HW_ + p] = acc[oa][pb][r];
            }
}

// ---- batchnorm stats ----
__global__ __launch_bounds__(256) void bn_stats_kernel(
    const float* __restrict__ hbuf, float* __restrict__ stats)
{
    const int c = blockIdx.x;
    const int t = threadIdx.x;
    float s = 0.f, s2 = 0.f;
    for (int b = 0; b < B_; ++b) {
        const float* p = hbuf + (size_t)(b * C_ + c) * DHW_;
        for (int i = t; i < DHW_; i += 256) {
            float v = p[i];
            s += v; s2 += v * v;
        }
    }
    #pragma unroll
    for (int o = 32; o > 0; o >>= 1) {
        s  += __shfl_down(s, o);
        s2 += __shfl_down(s2, o);
    }
    __shared__ float rs[4], rq[4];
    if ((t & 63) == 0) { rs[t >> 6] = s; rq[t >> 6] = s2; }
    __syncthreads();
    if (t == 0) {
        float ts = rs[0] + rs[1] + rs[2] + rs[3];
        float tq = rq[0] + rq[1] + rq[2] + rq[3];
        float inv = 1.f / (float)(B_ * DHW_);
        float m   = ts * inv;
        float var = tq * inv - m * m;
        stats[c]      = m;
        stats[C_ + c] = rsqrtf(fmaxf(var, 0.f) + 1e-5f);
    }
}

// ---- bn + relu + pack to bf16 [b][g][dhw][c8] ----
__global__ __launch_bounds__(256) void bn_relu_pack_kernel(
    const float* __restrict__ h, const float* __restrict__ stats,
    const float* __restrict__ gamma, const float* __restrict__ beta,
    unsigned short* __restrict__ out)
{
    int i = blockIdx.x * 256 + threadIdx.x;          // over B*G*DHW
    if (i >= B_ * G_ * DHW_) return;
    int b = i / (G_ * DHW_);
    int rem = i - b * G_ * DHW_;
    int g = rem / DHW_, dhw = rem - g * DHW_;
    ushort8 o8;
    #pragma unroll
    for (int c = 0; c < 8; ++c) {
        int ch = g * 8 + c;
        float v = (h[(size_t)(b * C_ + ch) * DHW_ + dhw] - stats[ch]) * stats[C_ + ch] * gamma[ch] + beta[ch];
        o8[c] = f2bf(v > 0.f ? v : 0.f);
    }
    *(ushort8*)(out + (size_t)i * 8) = o8;
}

// ---- bn + residual + relu (in place on d_out) ----
__global__ __launch_bounds__(256) void bn_add_relu_kernel(
    float* __restrict__ hbuf, const float* __restrict__ xres,
    const float* __restrict__ stats,
    const float* __restrict__ gamma, const float* __restrict__ beta)
{
    const int n = B_ * C_ * DHW_;
    for (int i = blockIdx.x * 256 + threadIdx.x; i < n; i += gridDim.x * 256) {
        int c = (i / DHW_) & (C_ - 1);
        float v = (hbuf[i] - stats[c]) * stats[C_ + c] * gamma[c] + beta[c] + xres[i];
        hbuf[i] = v > 0.f ? v : 0.f;
    }
}

extern "C" void kernel_launch(void* const* d_in, const int* in_sizes, int n_in,
                              void* d_out, int out_size, void* d_ws, size_t ws_size,
                              hipStream_t stream)
{
    const float* x      = (const float*)d_in[0];
    const float* w_off1 = (const float*)d_in[1];
    const float* b_off1 = (const float*)d_in[2];
    const float* w_dc1  = (const float*)d_in[3];
    const float* gamma1 = (const float*)d_in[4];
    const float* beta1  = (const float*)d_in[5];
    const float* w_off2 = (const float*)d_in[6];
    const float* b_off2 = (const float*)d_in[7];
    const float* w_dc2  = (const float*)d_in[8];
    const float* gamma2 = (const float*)d_in[9];
    const float* beta2  = (const float*)d_in[10];
    float* out = (float*)d_out;

    // ws layout (bf16 first, then f32) — total ~93 MB
    unsigned short* offb = (unsigned short*)d_ws;                    // 32,514,048
    unsigned short* xp   = offb + (size_t)B_ * OFFC_ * DHW_;         //  3,211,264
    unsigned short* h1p  = xp   + (size_t)B_ * G_ * DHW_ * 8;        //  3,211,264
    unsigned short* wT   = h1p  + (size_t)B_ * G_ * DHW_ * 8;        //  1,119,744
    unsigned short* wdcT = wT   + (size_t)OFFC_ * 1728;              //    110,592
    float* h1raw = (float*)(wdcT + (size_t)C_ * 1728);               //  3,211,264 f32
    float* stats = h1raw + (size_t)B_ * C_ * DHW_;                   //  128 f32

    dim3 cgrid(11, 49, B_ * D_);
    dim3 dgrid(49, B_ * D_);
    const int pgrid = (B_ * G_ * DHW_ + 255) / 256;      // 1568
    const int tg1   = (OFFC_ * 1728 + 255) / 256;
    const int tg2   = (C_ * 1728 + 255) / 256;

    pack_kernel         <<<pgrid, 256, 0, stream>>>(x, xp);
    wt_transpose_kernel <<<tg1, 256, 0, stream>>>(w_off1, wT, OFFC_ * 1728);
    wt_transpose_kernel <<<tg2, 256, 0, stream>>>(w_dc1, wdcT, C_ * 1728);
    conv_off_mfma_kernel<<<cgrid, 256, 0, stream>>>(xp, wT, b_off1, offb);
    deform_mfma_kernel  <<<dgrid, 256, 0, stream>>>(xp, offb, wdcT, h1raw);
    bn_stats_kernel     <<<C_, 256, 0, stream>>>(h1raw, stats);
    bn_relu_pack_kernel <<<pgrid, 256, 0, stream>>>(h1raw, stats, gamma1, beta1, h1p);

    wt_transpose_kernel <<<tg1, 256, 0, stream>>>(w_off2, wT, OFFC_ * 1728);
    wt_transpose_kernel <<<tg2, 256, 0, stream>>>(w_dc2, wdcT, C_ * 1728);
    conv_off_mfma_kernel<<<cgrid, 256, 0, stream>>>(h1p, wT, b_off2, offb);
    deform_mfma_kernel  <<<dgrid, 256, 0, stream>>>(h1p, offb, wdcT, out);
    bn_stats_kernel     <<<C_, 256, 0, stream>>>(out, stats);
    bn_add_relu_kernel  <<<1024, 256, 0, stream>>>(out, x, stats, gamma2, beta2);
}

// Round 4
// 1039.810 us; speedup vs baseline: 13.5910x; 2.5617x over previous
//
#include <hip/hip_runtime.h>

#define B_    2
#define C_    64
#define D_    8
#define H_    56
#define W_    56
#define HW_   3136
#define DHW_  25088
#define G_    8
#define K_    27
#define OFFC_ 648

typedef __attribute__((ext_vector_type(8))) short  bf16x8;
typedef __attribute__((ext_vector_type(4))) float  f32x4;
typedef __attribute__((ext_vector_type(8))) unsigned short ushort8;

__device__ __forceinline__ unsigned short f2bf(float f) {
    unsigned u = __float_as_uint(f);
    u = (u + 0x7FFFu + ((u >> 16) & 1u)) >> 16;
    return (unsigned short)u;
}
__device__ __forceinline__ float bf2f(unsigned short u) {
    return __uint_as_float(((unsigned)u) << 16);
}

// ---- pack x: f32 [b][c][d][h][w] -> bf16 [b][g][d][h][w][c8] ----
__global__ __launch_bounds__(256) void pack_kernel(
    const float* __restrict__ x, unsigned short* __restrict__ xp)
{
    int i = blockIdx.x * 256 + threadIdx.x;
    if (i >= B_ * G_ * DHW_) return;
    int b = i / (G_ * DHW_);
    int rem = i - b * G_ * DHW_;
    int g = rem / DHW_, dhw = rem - g * DHW_;
    const float* src = x + (size_t)(b * C_ + g * 8) * DHW_ + dhw;
    ushort8 v;
    #pragma unroll
    for (int c = 0; c < 8; ++c) v[c] = f2bf(src[c * DHW_]);
    *(ushort8*)(xp + (size_t)i * 8) = v;
}

// ---- weight transpose: w[oc][ic][27] f32 -> wT[oc][g*216 + tap*8 + c] bf16 ----
__global__ __launch_bounds__(256) void wt_transpose_kernel(
    const float* __restrict__ wt, unsigned short* __restrict__ wT, int total)
{
    int i = blockIdx.x * 256 + threadIdx.x;
    if (i >= total) return;
    int oc = i / 1728, k = i - oc * 1728;
    int icc = k / 216, r = k - icc * 216;
    int tap = r >> 3, icl = r & 7;
    wT[i] = f2bf(wt[(size_t)oc * 1728 + (icc * 8 + icl) * 27 + tap]);
}

#define CROW 512
__device__ __forceinline__ int swz(int row, int kByte) {
    return row * CROW + (kByte ^ ((row & 7) << 4));
}

// ---- offset conv implicit GEMM v3: no materialized im2col ----
// grid (11, 25, 16). block 256 = 4 waves (2 oc x 2 pos). tile 64 oc x 128 pos.
__global__ __launch_bounds__(256, 3) void conv_off_mfma_kernel(
    const unsigned short* __restrict__ xp, const unsigned short* __restrict__ wT,
    const float* __restrict__ bias, unsigned short* __restrict__ out)
{
    __shared__ __align__(16) char wb[64 * CROW];              // 32 KB, slot 27 zeroed
    __shared__ __align__(16) unsigned short xr[3 * 6 * 64 * 8]; // 18 KB raw patch
    __shared__ __align__(16) unsigned short zpad[8];          // 16 B zeros

    const int oc0  = blockIdx.x * 64;
    const int pos0 = blockIdx.y * 128;
    const int b    = blockIdx.z >> 3;
    const int d    = blockIdx.z & 7;
    const int h0   = pos0 / 56;
    const int t    = threadIdx.x;
    const int lane = t & 63;
    const int li   = lane & 15;
    const int ts   = lane >> 4;
    const int wv   = t >> 6;
    const int wrow = wv >> 1, wcol = wv & 1;

    if (t == 0) *(ushort8*)zpad = (ushort8){0,0,0,0,0,0,0,0};

    // precompute per-lane fragment address pieces (element-of-16B units)
    int poff[4];
    #pragma unroll
    for (int pb = 0; pb < 4; ++pb) {
        int pl = wcol * 64 + pb * 16 + li;
        int p  = pos0 + pl;
        int hp = p / 56, wp = p - hp * 56;
        poff[pb] = (hp - h0) * 64 + wp;
    }
    int offk[7];
    #pragma unroll
    for (int kk = 0; kk < 7; ++kk) {
        int tap = 4 * kk + ts;            // <= 27
        int dd = tap / 9, hh = (tap / 3) % 3, ww = tap - (tap / 3) * 3;
        offk[kk] = (dd * 6 + hh) * 64 + ww;   // tap==27 value never used
    }

    f32x4 acc[2][4];
    #pragma unroll
    for (int i = 0; i < 2; ++i)
        #pragma unroll
        for (int j = 0; j < 4; ++j) acc[i][j] = (f32x4){0.f, 0.f, 0.f, 0.f};

    for (int g = 0; g < 8; ++g) {
        __syncthreads();
        // stage raw patch: xr[dd3][hl6][w64][c8]; src (d+dd-1, h0+hl-1, w-1)
        for (int i = t; i < 1152; i += 256) {
            int w = i & 63, rest = i >> 6;
            int hl = rest % 6, dd = rest / 6;
            int ds = d + dd - 1, hs = h0 + hl - 1, wsrc = w - 1;
            ushort8 v = {0, 0, 0, 0, 0, 0, 0, 0};
            if ((unsigned)ds < 8u && (unsigned)hs < 56u && (unsigned)wsrc < 56u)
                v = *(const ushort8*)(xp + ((size_t)((b * 8 + g) * 8 + ds) * HW_ + hs * 56 + wsrc) * 8);
            *(ushort8*)&xr[i * 8] = v;
        }
        // stage weights: 64 oc x 28 b128 slots (slot 27 = zeros)
        for (int i = t; i < 1792; i += 256) {
            int row = i / 28, slot = i - row * 28;
            ushort8 v = {0, 0, 0, 0, 0, 0, 0, 0};
            int ocg = oc0 + row;
            if (slot < 27 && ocg < OFFC_)
                v = *(const ushort8*)(wT + (size_t)ocg * 1728 + g * 216 + slot * 8);
            *(ushort8*)(wb + swz(row, slot * 16)) = v;
        }
        __syncthreads();
        #pragma unroll
        for (int kk = 0; kk < 7; ++kk) {
            int tap = 4 * kk + ts;
            bf16x8 a0 = *(const bf16x8*)(wb + swz(wrow * 32 +      li, tap * 16));
            bf16x8 a1 = *(const bf16x8*)(wb + swz(wrow * 32 + 16 + li, tap * 16));
            bf16x8 bf[4];
            #pragma unroll
            for (int pb = 0; pb < 4; ++pb) {
                const void* ba = (kk < 6 || ts < 3)
                    ? (const void*)&xr[(offk[kk] + poff[pb]) * 8]
                    : (const void*)zpad;
                bf[pb] = *(const bf16x8*)ba;
            }
            #pragma unroll
            for (int pb = 0; pb < 4; ++pb) {
                acc[0][pb] = __builtin_amdgcn_mfma_f32_16x16x32_bf16(a0, bf[pb], acc[0][pb], 0, 0, 0);
                acc[1][pb] = __builtin_amdgcn_mfma_f32_16x16x32_bf16(a1, bf[pb], acc[1][pb], 0, 0, 0);
            }
        }
    }

    #pragma unroll
    for (int oa = 0; oa < 2; ++oa)
        #pragma unroll
        for (int pb = 0; pb < 4; ++pb)
            #pragma unroll
            for (int r = 0; r < 4; ++r) {
                int ocg = oc0 + wrow * 32 + oa * 16 + ts * 4 + r;
                int p   = pos0 + wcol * 64 + pb * 16 + li;
                if (ocg < OFFC_ && p < HW_)
                    out[((size_t)(b * OFFC_ + ocg) * 8 + d) * HW_ + p] = f2bf(acc[oa][pb][r] + bias[ocg]);
            }
}

// ---- deformable conv implicit GEMM (unchanged) ----
__global__ __launch_bounds__(256) void deform_mfma_kernel(
    const unsigned short* __restrict__ xp, const unsigned short* __restrict__ off,
    const unsigned short* __restrict__ wT, float* __restrict__ out)
{
    __shared__ __align__(16) char colb[64 * CROW];
    __shared__ __align__(16) char wb[64 * CROW];

    const int pos0 = blockIdx.x * 64;
    const int b    = blockIdx.y >> 3;
    const int d    = blockIdx.y & 7;
    const int t    = threadIdx.x;
    const int lane = t & 63, wv = t >> 6;
    const int wrow = wv >> 1, wcol = wv & 1;

    f32x4 acc[2][2];
    #pragma unroll
    for (int i = 0; i < 2; ++i)
        #pragma unroll
        for (int j = 0; j < 2; ++j) acc[i][j] = (f32x4){0.f, 0.f, 0.f, 0.f};

    for (int g = 0; g < 8; ++g) {
        __syncthreads();
        for (int i = t; i < 7168; i += 256) {
            int oc = i / 112, k2 = i - oc * 112, k = k2 * 2;
            unsigned vv = (k < 216) ? *(const unsigned*)(wT + (size_t)oc * 1728 + g * 216 + k) : 0u;
            *(unsigned*)(wb + swz(oc, k2 * 4)) = vv;
        }
        for (int i = t; i < 1728; i += 256) {
            int pos = i & 63, kk = i >> 6;
            int p = pos0 + pos;
            int hq = p / 56, wq = p - hq * 56;
            int kd = kk / 9 - 1, kh = (kk / 3) % 3 - 1, kw = kk - (kk / 3) * 3 - 1;
            size_t ob = ((size_t)(b * OFFC_ + (g * 27 + kk) * 3) * 8 + d) * HW_ + p;
            float pd = bf2f(off[ob])            + (float)(kd + d);
            float ph = bf2f(off[ob + DHW_])     + (float)(kh + hq);
            float pw = bf2f(off[ob + 2 * DHW_]) + (float)(kw + wq);
            float fd0 = floorf(pd), fh0 = floorf(ph), fw0 = floorf(pw);
            float fd = pd - fd0, fh = ph - fh0, fw = pw - fw0;
            int d0 = (int)fd0, h0i = (int)fh0, w0i = (int)fw0;
            const unsigned short* xb = xp + (size_t)(b * 8 + g) * 8 * HW_ * 8;
            float a[8] = {0.f, 0.f, 0.f, 0.f, 0.f, 0.f, 0.f, 0.f};
            #pragma unroll
            for (int tp = 0; tp < 8; ++tp) {
                int dd = tp >> 2, hh = (tp >> 1) & 1, ww = tp & 1;
                int di = d0 + dd, hi = h0i + hh, wi = w0i + ww;
                float wgt = (dd ? fd : 1.f - fd) * (hh ? fh : 1.f - fh) * (ww ? fw : 1.f - fw);
                bool valid = ((unsigned)di < 8u) && ((unsigned)hi < 56u) && ((unsigned)wi < 56u);
                wgt = valid ? wgt : 0.f;
                int dc = valid ? di : 0, hc = valid ? hi : 0, wc = valid ? wi : 0;
                ushort8 v = *(const ushort8*)(xb + ((size_t)dc * HW_ + hc * 56 + wc) * 8);
                #pragma unroll
                for (int c = 0; c < 8; ++c) a[c] += bf2f(v[c]) * wgt;
            }
            ushort8 o8;
            #pragma unroll
            for (int c = 0; c < 8; ++c) o8[c] = f2bf(a[c]);
            *(ushort8*)(colb + swz(pos, kk * 16)) = o8;
        }
        if (t < 64) {
            ushort8 z = {0, 0, 0, 0, 0, 0, 0, 0};
            *(ushort8*)(colb + swz(t, 432)) = z;
        }
        __syncthreads();
        #pragma unroll
        for (int kk = 0; kk < 7; ++kk) {
            int kb = kk * 64 + (lane >> 4) * 16;
            bf16x8 a0 = *(const bf16x8*)(wb   + swz(wrow * 32 +      (lane & 15), kb));
            bf16x8 a1 = *(const bf16x8*)(wb   + swz(wrow * 32 + 16 + (lane & 15), kb));
            bf16x8 b0 = *(const bf16x8*)(colb + swz(wcol * 32 +      (lane & 15), kb));
            bf16x8 b1 = *(const bf16x8*)(colb + swz(wcol * 32 + 16 + (lane & 15), kb));
            acc[0][0] = __builtin_amdgcn_mfma_f32_16x16x32_bf16(a0, b0, acc[0][0], 0, 0, 0);
            acc[0][1] = __builtin_amdgcn_mfma_f32_16x16x32_bf16(a0, b1, acc[0][1], 0, 0, 0);
            acc[1][0] = __builtin_amdgcn_mfma_f32_16x16x32_bf16(a1, b0, acc[1][0], 0, 0, 0);
            acc[1][1] = __builtin_amdgcn_mfma_f32_16x16x32_bf16(a1, b1, acc[1][1], 0, 0, 0);
        }
    }

    #pragma unroll
    for (int oa = 0; oa < 2; ++oa)
        #pragma unroll
        for (int pb = 0; pb < 2; ++pb)
            #pragma unroll
            for (int r = 0; r < 4; ++r) {
                int oc = wrow * 32 + oa * 16 + (lane >> 4) * 4 + r;
                int p  = pos0 + wcol * 32 + pb * 16 + (lane & 15);
                out[((size_t)(b * C_ + oc) * 8 + d) * HW_ + p] = acc[oa][pb][r];
            }
}

// ---- batchnorm stats, two-stage ----
__global__ __launch_bounds__(256) void bn_stats_partial_kernel(
    const float* __restrict__ h, float* __restrict__ part)
{
    const int c = blockIdx.x, s = blockIdx.y;
    const int t = threadIdx.x;
    const int SL = (B_ * DHW_) / 16;           // 3136
    float sum = 0.f, sq = 0.f;
    for (int j = s * SL + t; j < (s + 1) * SL; j += 256) {
        int b = j / DHW_, i = j - b * DHW_;
        float v = h[(size_t)(b * C_ + c) * DHW_ + i];
        sum += v; sq += v * v;
    }
    #pragma unroll
    for (int o = 32; o > 0; o >>= 1) {
        sum += __shfl_down(sum, o);
        sq  += __shfl_down(sq, o);
    }
    __shared__ float rs[4], rq[4];
    if ((t & 63) == 0) { rs[t >> 6] = sum; rq[t >> 6] = sq; }
    __syncthreads();
    if (t == 0) {
        part[c * 16 + s]        = rs[0] + rs[1] + rs[2] + rs[3];
        part[1024 + c * 16 + s] = rq[0] + rq[1] + rq[2] + rq[3];
    }
}

__global__ void bn_stats_finalize_kernel(
    const float* __restrict__ part, float* __restrict__ stats)
{
    int c = threadIdx.x;
    if (c >= 64) return;
    float s = 0.f, q = 0.f;
    for (int i = 0; i < 16; ++i) { s += part[c * 16 + i]; q += part[1024 + c * 16 + i]; }
    float inv = 1.f / (float)(B_ * DHW_);
    float m   = s * inv;
    float var = q * inv - m * m;
    stats[c]      = m;
    stats[C_ + c] = rsqrtf(fmaxf(var, 0.f) + 1e-5f);
}

// ---- bn + relu + pack to bf16 [b][g][dhw][c8] ----
__global__ __launch_bounds__(256) void bn_relu_pack_kernel(
    const float* __restrict__ h, const float* __restrict__ stats,
    const float* __restrict__ gamma, const float* __restrict__ beta,
    unsigned short* __restrict__ out)
{
    int i = blockIdx.x * 256 + threadIdx.x;
    if (i >= B_ * G_ * DHW_) return;
    int b = i / (G_ * DHW_);
    int rem = i - b * G_ * DHW_;
    int g = rem / DHW_, dhw = rem - g * DHW_;
    ushort8 o8;
    #pragma unroll
    for (int c = 0; c < 8; ++c) {
        int ch = g * 8 + c;
        float v = (h[(size_t)(b * C_ + ch) * DHW_ + dhw] - stats[ch]) * stats[C_ + ch] * gamma[ch] + beta[ch];
        o8[c] = f2bf(v > 0.f ? v : 0.f);
    }
    *(ushort8*)(out + (size_t)i * 8) = o8;
}

// ---- bn + residual + relu (in place on d_out) ----
__global__ __launch_bounds__(256) void bn_add_relu_kernel(
    float* __restrict__ hbuf, const float* __restrict__ xres,
    const float* __restrict__ stats,
    const float* __restrict__ gamma, const float* __restrict__ beta)
{
    const int n = B_ * C_ * DHW_;
    for (int i = blockIdx.x * 256 + threadIdx.x; i < n; i += gridDim.x * 256) {
        int c = (i / DHW_) & (C_ - 1);
        float v = (hbuf[i] - stats[c]) * stats[C_ + c] * gamma[c] + beta[c] + xres[i];
        hbuf[i] = v > 0.f ? v : 0.f;
    }
}

extern "C" void kernel_launch(void* const* d_in, const int* in_sizes, int n_in,
                              void* d_out, int out_size, void* d_ws, size_t ws_size,
                              hipStream_t stream)
{
    const float* x      = (const float*)d_in[0];
    const float* w_off1 = (const float*)d_in[1];
    const float* b_off1 = (const float*)d_in[2];
    const float* w_dc1  = (const float*)d_in[3];
    const float* gamma1 = (const float*)d_in[4];
    const float* beta1  = (const float*)d_in[5];
    const float* w_off2 = (const float*)d_in[6];
    const float* b_off2 = (const float*)d_in[7];
    const float* w_dc2  = (const float*)d_in[8];
    const float* gamma2 = (const float*)d_in[9];
    const float* beta2  = (const float*)d_in[10];
    float* out = (float*)d_out;

    unsigned short* offb = (unsigned short*)d_ws;                    // 32,514,048
    unsigned short* xp   = offb + (size_t)B_ * OFFC_ * DHW_;         //  3,211,264
    unsigned short* h1p  = xp   + (size_t)B_ * G_ * DHW_ * 8;        //  3,211,264
    unsigned short* wT   = h1p  + (size_t)B_ * G_ * DHW_ * 8;        //  1,119,744
    unsigned short* wdcT = wT   + (size_t)OFFC_ * 1728;              //    110,592
    float* h1raw = (float*)(wdcT + (size_t)C_ * 1728);               //  3,211,264 f32
    float* stats = h1raw + (size_t)B_ * C_ * DHW_;                   //  128 f32
    float* part  = stats + 128;                                      //  2048 f32

    dim3 cgrid(11, 25, B_ * D_);
    dim3 dgrid(49, B_ * D_);
    dim3 sgrid(C_, 16);
    const int pgrid = (B_ * G_ * DHW_ + 255) / 256;
    const int tg1   = (OFFC_ * 1728 + 255) / 256;
    const int tg2   = (C_ * 1728 + 255) / 256;

    pack_kernel            <<<pgrid, 256, 0, stream>>>(x, xp);
    wt_transpose_kernel    <<<tg1, 256, 0, stream>>>(w_off1, wT, OFFC_ * 1728);
    wt_transpose_kernel    <<<tg2, 256, 0, stream>>>(w_dc1, wdcT, C_ * 1728);
    conv_off_mfma_kernel   <<<cgrid, 256, 0, stream>>>(xp, wT, b_off1, offb);
    deform_mfma_kernel     <<<dgrid, 256, 0, stream>>>(xp, offb, wdcT, h1raw);
    bn_stats_partial_kernel<<<sgrid, 256, 0, stream>>>(h1raw, part);
    bn_stats_finalize_kernel<<<1, 64, 0, stream>>>(part, stats);
    bn_relu_pack_kernel    <<<pgrid, 256, 0, stream>>>(h1raw, stats, gamma1, beta1, h1p);

    wt_transpose_kernel    <<<tg1, 256, 0, stream>>>(w_off2, wT, OFFC_ * 1728);
    wt_transpose_kernel    <<<tg2, 256, 0, stream>>>(w_dc2, wdcT, C_ * 1728);
    conv_off_mfma_kernel   <<<cgrid, 256, 0, stream>>>(h1p, wT, b_off2, offb);
    deform_mfma_kernel     <<<dgrid, 256, 0, stream>>>(h1p, offb, wdcT, out);
    bn_stats_partial_kernel<<<sgrid, 256, 0, stream>>>(out, part);
    bn_stats_finalize_kernel<<<1, 64, 0, stream>>>(part, stats);
    bn_add_relu_kernel     <<<1024, 256, 0, stream>>>(out, x, stats, gamma2, beta2);
}